// Round 10
// baseline (54.990 us; speedup 1.0000x reference)
//
#include <hip/hip_runtime.h>
#include <math.h>

#define B_ 4
#define N_ 32768
#define M_ 8192
#define K_ 16
#define D_ 64
#define O_ 64

typedef __attribute__((ext_vector_type(8))) short bf16x8;
typedef __attribute__((ext_vector_type(4))) float f32x4;

// float -> bf16 bits, round-to-nearest-even (inputs are finite normals)
static __device__ __forceinline__ short f2bf(float f) {
    unsigned u = __float_as_uint(f);
    u += 0x7fffu + ((u >> 16) & 1u);
    return (short)(u >> 16);
}

// 8 consecutive floats -> bf16x8 (one MFMA k-chunk)
static __device__ __forceinline__ bf16x8 ld_bf8(const float* p) {
    float4 f0 = *(const float4*)p;
    float4 f1 = *(const float4*)(p + 4);
    bf16x8 v;
    v[0] = f2bf(f0.x); v[1] = f2bf(f0.y); v[2] = f2bf(f0.z); v[3] = f2bf(f0.w);
    v[4] = f2bf(f1.x); v[5] = f2bf(f1.y); v[6] = f2bf(f1.z); v[7] = f2bf(f1.w);
    return v;
}

// ---------------------------------------------------------------------------
// Fused kernel (R10 = R9 + occupancy fix):
//   out[b,o,m] = relu( max_k (x[b,idx[m,k]].W1[o]) + xs[b,m].(W2-W1)[o] + b[o] )
// R9 diagnosis: wave=16m forced 2048 waves total (2/SIMD) -> latency-bound
// (MfmaUtil 3%, VALU 13%, HBM 18%). R10: wave = 4 m, block = 4 waves = 16 m,
// grid = 2048 blocks -> 8192 waves (VGPR-capped ~4-5/SIMD, 2-2.5x R9).
// Center term: every wave MFMAs the block's 16 xs rows (bias-init, 4x
// redundant = 8 MFMA/wave, negligible); lane(kg==wv) owns rows wv*4+r.
// Gather-max per m: A-frag = 16 neighbor rows (lane lr -> idx[m][lr],
// k-chunk kg*8 + s*32), 8 MFMAs vs resident W1 frags, in-lane fmax over 4
// regs + shfl_xor(16,32) -> all lanes hold gmax. Epilogue on owner lanes,
// LDS transpose [64][17], coalesced 64B-segment stores.
// Batch-affine XCD swizzle: XCD pair {2c,2c+1} -> batch c (bijective).
// ---------------------------------------------------------------------------
__global__ __launch_bounds__(256)
void fused_gconv(const float* __restrict__ x, const float* __restrict__ xs,
                 const int* __restrict__ idx, const float* __restrict__ W,
                 const float* __restrict__ bias, float* __restrict__ out) {
    __shared__ int   ldsI[256];        // 16 m x 16 k indices
    __shared__ float ldsT[64 * 17];    // [o][m] transpose

    const int tid  = threadIdx.x;
    const int blk  = blockIdx.x;       // 0..2047
    const int xcd  = blk & 7;
    const int slot = blk >> 3;         // 0..255
    const int bb   = xcd >> 1;         // batch on XCD pair
    const int m0   = (((xcd & 1) << 8) + slot) << 4;   // batch-local m base

    // stage idx: 1KB, fully coalesced
    ldsI[tid] = idx[((size_t)bb * M_ + m0) * 16 + tid];

    const int l  = tid & 63;
    const int wv = tid >> 6;           // wave -> m group wv*4..wv*4+3
    const int lr = l & 15;
    const int kg = l >> 4;

    // resident fragments: W1 and (W2-W1); o-col = t*16+lr, k = s*32+kg*8..
    bf16x8 b1[2][4], bd[2][4];
    float  binit[4];
    #pragma unroll
    for (int t = 0; t < 4; ++t) {
        #pragma unroll
        for (int s = 0; s < 2; ++s) {
            const float* wp = W + (size_t)(t * 16 + lr) * 128 + s * 32 + kg * 8;
            float4 f0 = *(const float4*)wp;
            float4 f1 = *(const float4*)(wp + 4);
            float4 g0 = *(const float4*)(wp + 64);
            float4 g1 = *(const float4*)(wp + 68);
            bf16x8 v1, vd;
            v1[0] = f2bf(f0.x); v1[1] = f2bf(f0.y); v1[2] = f2bf(f0.z); v1[3] = f2bf(f0.w);
            v1[4] = f2bf(f1.x); v1[5] = f2bf(f1.y); v1[6] = f2bf(f1.z); v1[7] = f2bf(f1.w);
            vd[0] = f2bf(g0.x - f0.x); vd[1] = f2bf(g0.y - f0.y);
            vd[2] = f2bf(g0.z - f0.z); vd[3] = f2bf(g0.w - f0.w);
            vd[4] = f2bf(g1.x - f1.x); vd[5] = f2bf(g1.y - f1.y);
            vd[6] = f2bf(g1.z - f1.z); vd[7] = f2bf(g1.w - f1.w);
            b1[s][t] = v1;
            bd[s][t] = vd;
        }
        binit[t] = bias[t * 16 + lr];
    }

    // center: block's 16 xs rows vs (W2-W1), bias-init.
    // D rows m_tile = kg*4 + r; wave wv's m live in lanes kg==wv.
    const float* xsp = xs + ((size_t)bb * M_ + m0 + lr) * 64 + kg * 8;
    bf16x8 axs0 = ld_bf8(xsp);
    bf16x8 axs1 = ld_bf8(xsp + 32);
    f32x4 cacc[4];
    #pragma unroll
    for (int t = 0; t < 4; ++t) {
        f32x4 a = {binit[t], binit[t], binit[t], binit[t]};
        a = __builtin_amdgcn_mfma_f32_16x16x32_bf16(axs0, bd[0][t], a, 0, 0, 0);
        a = __builtin_amdgcn_mfma_f32_16x16x32_bf16(axs1, bd[1][t], a, 0, 0, 0);
        cacc[t] = a;
    }

    __syncthreads();                   // ldsI ready

    const float* xb = x + (size_t)bb * N_ * 64;

    // gather-max for this wave's 4 m (full unroll -> static indexing)
    float gmax[4][4];                  // [t][j]
    #pragma unroll
    for (int j = 0; j < 4; ++j) {
        const int rr = ldsI[(wv * 4 + j) * 16 + lr];   // 16-lane broadcast
        const float* xp = xb + (size_t)(unsigned)rr * 64 + kg * 8;
        bf16x8 a0 = ld_bf8(xp);
        bf16x8 a1 = ld_bf8(xp + 32);
        #pragma unroll
        for (int t = 0; t < 4; ++t) {
            f32x4 a = {0.f, 0.f, 0.f, 0.f};
            a = __builtin_amdgcn_mfma_f32_16x16x32_bf16(a0, b1[0][t], a, 0, 0, 0);
            a = __builtin_amdgcn_mfma_f32_16x16x32_bf16(a1, b1[1][t], a, 0, 0, 0);
            float v = fmaxf(fmaxf(a[0], a[1]), fmaxf(a[2], a[3]));
            v = fmaxf(v, __shfl_xor(v, 16));
            v = fmaxf(v, __shfl_xor(v, 32));           // max over 16 k-rows
            gmax[t][j] = v;                            // same in all lanes
        }
    }

    // epilogue: owner lanes (kg == wv) combine + relu + transpose write
    if (kg == wv) {
        #pragma unroll
        for (int t = 0; t < 4; ++t)
            #pragma unroll
            for (int r = 0; r < 4; ++r) {
                float v = gmax[t][r] + cacc[t][r];
                ldsT[(t * 16 + lr) * 17 + wv * 4 + r] = v > 0.f ? v : 0.f;
            }
    }
    __syncthreads();

    // stores: thread tid -> o = tid>>2, 4 m at (tid&3)*4 (64B segments)
    const int o  = tid >> 2;
    const int mj = (tid & 3) * 4;
    const float* lp = &ldsT[o * 17 + mj];
    float4 v = make_float4(lp[0], lp[1], lp[2], lp[3]);
    *(float4*)(out + ((size_t)bb * 64 + o) * M_ + m0 + mj) = v;
}

extern "C" void kernel_launch(void* const* d_in, const int* in_sizes, int n_in,
                              void* d_out, int out_size, void* d_ws, size_t ws_size,
                              hipStream_t stream) {
    const float* x    = (const float*)d_in[0];
    const float* xs   = (const float*)d_in[1];
    const int*   idx  = (const int*)d_in[2];
    const float* W    = (const float*)d_in[3];
    const float* bias = (const float*)d_in[4];
    float* out = (float*)d_out;

    // 2048 blocks x 256 thr; block = 16 m, wave = 4 m
    fused_gconv<<<(B_ * M_) / 16, 256, 0, stream>>>(x, xs, idx, W, bias, out);
}

// Round 11
// 28.882 us; speedup vs baseline: 1.9039x; 1.9039x over previous
//
#include <hip/hip_runtime.h>
#include <math.h>

#define B_ 4
#define N_ 32768
#define M_ 8192
#define K_ 16
#define D_ 64
#define O_ 64

typedef __attribute__((ext_vector_type(8))) short bf16x8;
typedef __attribute__((ext_vector_type(4))) float f32x4;

// float -> bf16 bits, round-to-nearest-even (inputs are finite normals)
static __device__ __forceinline__ short f2bf(float f) {
    unsigned u = __float_as_uint(f);
    u += 0x7fffu + ((u >> 16) & 1u);
    return (short)(u >> 16);
}

// 8 consecutive floats -> bf16x8 (one MFMA k-chunk)
static __device__ __forceinline__ bf16x8 ld_bf8(const float* p) {
    float4 f0 = *(const float4*)p;
    float4 f1 = *(const float4*)(p + 4);
    bf16x8 v;
    v[0] = f2bf(f0.x); v[1] = f2bf(f0.y); v[2] = f2bf(f0.z); v[3] = f2bf(f0.w);
    v[4] = f2bf(f1.x); v[5] = f2bf(f1.y); v[6] = f2bf(f1.z); v[7] = f2bf(f1.w);
    return v;
}

// ---------------------------------------------------------------------------
// Fused kernel (R11 = R9 + de-serialization):
//   out[b,o,m] = relu( max_k (x[b,idx[m,k]].W1[o]) + xs[b,m].(W2-W1)[o] + b[o] )
// R10's A/B solved the cost model: c=1925 cy/m (serial chains), P=8800 cy
// prologue. Cause: per-m ds_read(idx) -> gather -> MFMA -> shfl(DS) chain;
// LDS ops complete IN ORDER, so issuing m+1's gather (needs its idx ds_read)
// waits on m's shfls -> full serialization. Fixes:
//   1) idx for all 16 m hoisted to VGPRs before the loop (no DS reads left
//      on the gather-issue path; gathers free-run under vmcnt).
//   2) W-frag conversion staged via LDS: wave wv converts t=wv only
//      (prologue global loads + f2bf VALU / 4), all waves read frags back.
// Structure otherwise = R9: 512 blocks x 4 waves, wave = 16 m.
// ---------------------------------------------------------------------------
__global__ __launch_bounds__(256)
void fused_gconv(const float* __restrict__ x, const float* __restrict__ xs,
                 const int* __restrict__ idx, const float* __restrict__ W,
                 const float* __restrict__ bias, float* __restrict__ out) {
    __shared__ int    ldsI[64 * 16];         // 4 KB: 64 m x 16 k
    __shared__ bf16x8 ldsW[4][2][2][64];     // 16 KB: [t][s][b1/bd][lane]
    __shared__ float  ldsB[64];
    __shared__ float  ldsT[64 * 65];         // transpose, stride 65

    const int tid  = threadIdx.x;
    const int blk  = blockIdx.x;       // 0..511
    const int bb   = blk >> 7;         // batch
    const int mblk = (blk & 127) * 64; // batch-local m base of block

    // stage idx: 4KB, fully coalesced (256 thr x int4)
    *(int4*)&ldsI[tid * 4] =
        *(const int4*)(idx + ((size_t)bb * M_ + mblk) * 16 + tid * 4);

    const int l  = tid & 63;
    const int wv = tid >> 6;           // wave id -> 16-m group, and W t-slice
    const int lr = l & 15;             // fragment row / col
    const int kg = l >> 4;             // k-group
    const int mw = wv * 16;            // group base within block

    // ---- W-frag stage: wave wv converts o-tile t=wv (b1 = W1, bd = W2-W1)
    {
        const int t = wv;
        #pragma unroll
        for (int s = 0; s < 2; ++s) {
            const float* wp = W + (size_t)(t * 16 + lr) * 128 + s * 32 + kg * 8;
            float4 f0 = *(const float4*)wp;
            float4 f1 = *(const float4*)(wp + 4);
            float4 g0 = *(const float4*)(wp + 64);
            float4 g1 = *(const float4*)(wp + 68);
            bf16x8 v1, vd;
            v1[0] = f2bf(f0.x); v1[1] = f2bf(f0.y); v1[2] = f2bf(f0.z); v1[3] = f2bf(f0.w);
            v1[4] = f2bf(f1.x); v1[5] = f2bf(f1.y); v1[6] = f2bf(f1.z); v1[7] = f2bf(f1.w);
            vd[0] = f2bf(g0.x - f0.x); vd[1] = f2bf(g0.y - f0.y);
            vd[2] = f2bf(g0.z - f0.z); vd[3] = f2bf(g0.w - f0.w);
            vd[4] = f2bf(g1.x - f1.x); vd[5] = f2bf(g1.y - f1.y);
            vd[6] = f2bf(g1.z - f1.z); vd[7] = f2bf(g1.w - f1.w);
            ldsW[t][s][0][l] = v1;
            ldsW[t][s][1][l] = vd;
        }
        if (tid < 64) ldsB[tid] = bias[tid];
    }
    __syncthreads();

    // read back full frag set (256B/thread from LDS) + bias
    bf16x8 b1[2][4], bd[2][4];
    float  binit[4];
    #pragma unroll
    for (int t = 0; t < 4; ++t) {
        #pragma unroll
        for (int s = 0; s < 2; ++s) {
            b1[s][t] = ldsW[t][s][0][l];
            bd[s][t] = ldsW[t][s][1][l];
        }
        binit[t] = ldsB[t * 16 + lr];
    }

    // center: wave's 16 xs rows vs (W2-W1), bias-init.
    const float* xsp = xs + ((size_t)bb * M_ + mblk + mw + lr) * 64 + kg * 8;
    bf16x8 axs0 = ld_bf8(xsp);
    bf16x8 axs1 = ld_bf8(xsp + 32);

    float vout[4][4];                  // [t][r]: o = t*16+lr, m = mw+kg*4+r
    #pragma unroll
    for (int t = 0; t < 4; ++t) {
        f32x4 a = {binit[t], binit[t], binit[t], binit[t]};
        a = __builtin_amdgcn_mfma_f32_16x16x32_bf16(axs0, bd[0][t], a, 0, 0, 0);
        a = __builtin_amdgcn_mfma_f32_16x16x32_bf16(axs1, bd[1][t], a, 0, 0, 0);
        vout[t][0] = a[0]; vout[t][1] = a[1];
        vout[t][2] = a[2]; vout[t][3] = a[3];
    }

    // ---- hoist ALL idx values to VGPRs (single lgkm wait; no DS read
    // remains on the gather-issue path inside the m-loop)
    int rr[16];
    #pragma unroll
    for (int m = 0; m < 16; ++m)
        rr[m] = ldsI[(mw + m) * 16 + lr];

    const float* xb = x + (size_t)bb * N_ * 64;

    // per-m: gather A-frag, 8 MFMAs, row-max (in-lane + 2 shfl), owner add.
    #pragma unroll
    for (int m = 0; m < 16; ++m) {
        const float* xp = xb + (size_t)(unsigned)rr[m] * 64 + kg * 8;
        bf16x8 a0 = ld_bf8(xp);
        bf16x8 a1 = ld_bf8(xp + 32);
        #pragma unroll
        for (int t = 0; t < 4; ++t) {
            f32x4 a = {0.f, 0.f, 0.f, 0.f};
            a = __builtin_amdgcn_mfma_f32_16x16x32_bf16(a0, b1[0][t], a, 0, 0, 0);
            a = __builtin_amdgcn_mfma_f32_16x16x32_bf16(a1, b1[1][t], a, 0, 0, 0);
            float v = fmaxf(fmaxf(a[0], a[1]), fmaxf(a[2], a[3]));
            v = fmaxf(v, __shfl_xor(v, 16));
            v = fmaxf(v, __shfl_xor(v, 32));           // max over 16 k-rows
            if ((m >> 2) == kg)                        // owner lane-group
                vout[t][m & 3] += v;
        }
    }

    // relu + LDS transpose write: [o = t*16+lr][m = mw + kg*4 + r]
    #pragma unroll
    for (int t = 0; t < 4; ++t)
        #pragma unroll
        for (int r = 0; r < 4; ++r) {
            float v = vout[t][r];
            ldsT[(t * 16 + lr) * 65 + mw + kg * 4 + r] = v > 0.f ? v : 0.f;
        }
    __syncthreads();

    // coalesced stores: thread tid -> o = tid>>2, 16 m at (tid&3)*16
    const int o  = tid >> 2;
    const int ms = (tid & 3) * 16;
    float* op = out + ((size_t)bb * 64 + o) * M_ + mblk + ms;
    #pragma unroll
    for (int j = 0; j < 4; ++j) {
        const float* lp = &ldsT[o * 65 + ms + j * 4];
        *(float4*)(op + j * 4) = make_float4(lp[0], lp[1], lp[2], lp[3]);
    }
}

extern "C" void kernel_launch(void* const* d_in, const int* in_sizes, int n_in,
                              void* d_out, int out_size, void* d_ws, size_t ws_size,
                              hipStream_t stream) {
    const float* x    = (const float*)d_in[0];
    const float* xs   = (const float*)d_in[1];
    const int*   idx  = (const int*)d_in[2];
    const float* W    = (const float*)d_in[3];
    const float* bias = (const float*)d_in[4];
    float* out = (float*)d_out;

    // 512 blocks x 256 thr; block = 64 m, wave = 16 m
    fused_gconv<<<(B_ * M_) / 64, 256, 0, stream>>>(x, xs, idx, W, bias, out);
}